// Round 6
// baseline (105.052 us; speedup 1.0000x reference)
//
#include <hip/hip_runtime.h>

// GGCARAFE: gradient-guided CARAFE upsample, B=8, C=256, H=W=64, K=3, S=2
// R6: k_comp jsplit 2 (x read 2x not 4x), k_out 4-outputs/thread + float2
// stores + XCD swizzle, ring-only zero merged into k_init.
// ws layout (float indices):
//   w1t   [256][64] f32         @ 0        (16384)   w1t[c*64+j] = w1[j][c]
//   mean  [B][H][W] f32         @ 16384    (32768)
//   mask  [B][H][W][4][9] f32   @ 49152    (1179648)
//   w2b   [48][576] bf16        @ 1228800  (13824 f32-equiv)  w2b[o][s*64+j]
//   comp_p[8][66][66][64] bf16  @ 1242624  (1115136 f32-equiv) zero ring
// total 2,357,760 floats = 9.43 MB

#define W1T_OFF   0
#define MEAN_OFF  16384
#define MASK_OFF  49152
#define W2B_OFF   1228800
#define CPP_OFF   1242624

typedef __attribute__((ext_vector_type(8))) short bf8;            // 8 bf16 = 16B
typedef __attribute__((ext_vector_type(8))) unsigned short us8;   // 16B store
typedef __attribute__((ext_vector_type(4))) float f4;
typedef __attribute__((ext_vector_type(2))) float f2;

static __device__ inline unsigned short f2bf(float f) {
    unsigned u = __float_as_uint(f);
    unsigned r = u + 0x7FFFu + ((u >> 16) & 1u);   // RNE
    return (unsigned short)(r >> 16);
}

// k_init: zero comp_p PAD RING only (interior overwritten by k_comp) + weight
// transposes. Ring = 260 px/batch x 8 x 128B = 16640 uint4 -> blocks 0..64.
// Blocks 65..132 do the transposes.
__global__ __launch_bounds__(256) void k_init(const float* __restrict__ w1,
                                              const float* __restrict__ w2,
                                              float* __restrict__ ws) {
    int bid = blockIdx.x, t = threadIdx.x;
    if (bid < 65) {
        int id = bid * 256 + t;           // 0..16639
        if (id < 16640) {
            int px = id >> 3, part = id & 7;
            int b = px / 260, r = px % 260;
            int y, xx;
            if (r < 66)       { y = 0;  xx = r; }
            else if (r < 132) { y = 65; xx = r - 66; }
            else              { int s = r - 132; y = (s & 63) + 1; xx = (s >> 6) ? 65 : 0; }
            uint4* p = (uint4*)((unsigned short*)(ws + CPP_OFF)
                                + ((size_t)(b * 66 + y) * 66 + xx) * 64) + part;
            *p = uint4{0, 0, 0, 0};
        }
        return;
    }
    float* w1t = ws + W1T_OFF;
    unsigned short* w2b = (unsigned short*)(ws + W2B_OFF);
    int gid = (bid - 65) * 256 + t;
    int stride = 68 * 256;
    for (int i = gid; i < 64 * 256; i += stride) {       // w1t[c][j] = w1[j][c]
        int c = i >> 6, j = i & 63;
        w1t[i] = w1[j * 256 + c];
    }
    for (int i = gid; i < 48 * 576; i += stride) {       // w2b[o][s*64+j]
        int o = i / 576, k = i % 576;
        int s = k >> 6, j = k & 63;
        w2b[i] = (o < 36) ? f2bf(w2[o * 576 + j * 9 + s]) : (unsigned short)0;
    }
}

// comp_p[b][h+1][w+1][jg*32..+32] bf16; mean fp32 (jg==0).
// grid 512 x 128: swizzled so the (jg=0,jg=1) pair of a pixblock shares an XCD
// L2 -> second x read is cache-served. x logical traffic 2x134 MB (was 4x).
__global__ __launch_bounds__(128) void k_comp(const float* __restrict__ x,
                                              const float* __restrict__ b1,
                                              float* __restrict__ ws) {
    const float* w1t = ws + W1T_OFF;
    float* mean = ws + MEAN_OFF;
    unsigned short* cpp = (unsigned short*)(ws + CPP_OFF);
    int bid = blockIdx.x;
    int swz = (bid & 7) * 64 + (bid >> 3);             // 512 = 8 x 64, bijective
    int jg = swz & 1;                                  // uniform
    int pix = (swz >> 1) * 128 + threadIdx.x;          // 0..32767
    int b = pix >> 12, hw = pix & 4095;
    int h = hw >> 6, wx = hw & 63;
    const float* xp = x + (size_t)b * 256 * 4096 + hw;
    float acc[32];
#pragma unroll
    for (int jj = 0; jj < 32; jj++) acc[jj] = b1[jg * 32 + jj];
    float msum = 0.f;
    for (int c = 0; c < 256; c += 16) {
        float xv[16];
#pragma unroll
        for (int u = 0; u < 16; u++) xv[u] = xp[(size_t)(c + u) * 4096];
#pragma unroll
        for (int u = 0; u < 16; u++) {
            msum += xv[u];
            const float* wp = w1t + (c + u) * 64 + jg * 32;   // uniform -> s_load
#pragma unroll
            for (int jj = 0; jj < 32; jj++) acc[jj] += wp[jj] * xv[u];
        }
    }
    unsigned short* dst = cpp + ((size_t)(b * 66 + h + 1) * 66 + (wx + 1)) * 64 + jg * 32;
#pragma unroll
    for (int v = 0; v < 4; v++) {
        us8 o;
#pragma unroll
        for (int jj = 0; jj < 8; jj++) o[jj] = f2bf(acc[v * 8 + jj]);
        *(us8*)(dst + v * 8) = o;
    }
    if (jg == 0) mean[pix] = msum * (1.f / 256.f);
}

// MFMA GEMM: kern[pixel][o] = A(comp patches) x B(w2b^T), then grad+softmax.
// grid 512 = (b,h) swizzled; block 384 = 6 waves: (o-tile = wid%3, half = wid/3).
__global__ __launch_bounds__(384) void k_mask(const float* __restrict__ b2,
                                              float* __restrict__ ws) {
    const unsigned short* w2b = (const unsigned short*)(ws + W2B_OFF);
    const unsigned short* cpp = (const unsigned short*)(ws + CPP_OFF);
    const float* mean = ws + MEAN_OFF;
    float* mask = ws + MASK_OFF;
    __shared__ float kern[64][49];   // +1 pad: conflict-free epilogue reads

    int bid = blockIdx.x;
    int swz = (bid & 7) * 64 + (bid >> 3);             // XCD chunking
    int b = swz >> 6, h = swz & 63;
    int t = threadIdx.x;
    int wid = __builtin_amdgcn_readfirstlane(t >> 6);  // 0..5, wave-uniform
    int l = t & 63;
    int o = wid % 3, ph = wid / 3;
    int lm = l & 15, lk = l >> 4;

    // 18 B-fragments held in VGPRs (one o-tile per wave)
    bf8 bfrag[18];
    const unsigned short* bp = w2b + (size_t)(o * 16 + lm) * 576 + lk * 8;
#pragma unroll
    for (int ks = 0; ks < 18; ks++) bfrag[ks] = *(const bf8*)(bp + ks * 32);

    // A base: pixel column lm, j-chunk lk*8, centered at padded (h, 0)
    const unsigned short* abase = cpp + ((size_t)(b * 66 + h) * 66 + lm) * 64 + lk * 8;

#pragma unroll
    for (int hf = 0; hf < 2; hf++) {
        int w0 = (ph * 2 + hf) * 16;
        const unsigned short* ab = abase + w0 * 64;
        f4 acc = {0.f, 0.f, 0.f, 0.f};
#pragma unroll
        for (int ks = 0; ks < 18; ks++) {
            const int s = ks >> 1, jh = ks & 1;
            const int dy = s / 3, dx = s % 3;          // compile-time
            bf8 af = *(const bf8*)(ab + (dy * 66 + dx) * 64 + jh * 32);
            acc = __builtin_amdgcn_mfma_f32_16x16x32_bf16(af, bfrag[ks], acc, 0, 0, 0);
        }
#pragma unroll
        for (int r = 0; r < 4; r++)
            kern[w0 + lk * 4 + r][o * 16 + lm] = acc[r];
    }
    __syncthreads();

    // epilogue: grad guidance + softmax; thread (w, pq) for t < 256
    if (t < 256) {
        int w = t & 63, pq = t >> 6;
        int pixel = (b * 64 + h) * 64 + w;
        float mc = mean[pixel];
        float v[9], mx = -1e30f;
#pragma unroll
        for (int kk = 0; kk < 9; kk++) {
            int y = h + kk / 3 - 1, xw = w + kk % 3 - 1;
            float mv = ((unsigned)y < 64u && (unsigned)xw < 64u)
                           ? mean[(b * 64 + y) * 64 + xw] : 0.f;
            float d = mv - mc;
            float g = 1.f / (d * d + 0.2f);
            v[kk] = g * (kern[w][kk * 4 + pq] + b2[kk * 4 + pq]);
            mx = fmaxf(mx, v[kk]);
        }
        float s = 0.f;
#pragma unroll
        for (int kk = 0; kk < 9; kk++) { v[kk] = __expf(v[kk] - mx); s += v[kk]; }
        float inv = 1.f / s;
        float* mout = mask + (size_t)pixel * 36 + pq * 9;
#pragma unroll
        for (int kk = 0; kk < 9; kk++) mout[kk] = v[kk] * inv;
    }
}

// out[b][c][2h+p][2w+q] = sum_kk x[b][c][h+dy-1][w+dx-1] * mask[..][p*2+q][kk]
// grid 2048 swizzled; thread (w = t&63, cs = t>>6): all 4 pq outputs per (c,w),
// float2 stores. c = cq*64 + cs, step 4 (16 iters).
__global__ __launch_bounds__(256) void k_out(const float* __restrict__ x,
                                             const float* __restrict__ ws,
                                             float* __restrict__ out) {
    const float* mask = ws + MASK_OFF;
    int bid = blockIdx.x;
    int swz = (bid & 7) * 256 + (bid >> 3);            // 2048 = 8 x 256
    int bh = swz >> 2, cq = swz & 3;
    int b = bh >> 6, h = bh & 63;
    int t = threadIdx.x;
    int w = t & 63, cs = t >> 6;

    const float* mrow = mask + (size_t)((b * 64 + h) * 64 + w) * 36;
    float m[4][9];
#pragma unroll
    for (int pq = 0; pq < 4; pq++) {
#pragma unroll
        for (int kk = 0; kk < 9; kk++) m[pq][kk] = mrow[pq * 9 + kk];
    }

    for (int c = cq * 64 + cs; c < cq * 64 + 64; c += 4) {
        const float* xb = x + (size_t)(b * 256 + c) * 4096;
        float p[3][3];
#pragma unroll
        for (int dy = 0; dy < 3; dy++) {
            int y = h + dy - 1;
            bool yok = (unsigned)y < 64u;
#pragma unroll
            for (int dx = 0; dx < 3; dx++) {
                int xx = w + dx - 1;
                p[dy][dx] = (yok && (unsigned)xx < 64u) ? xb[y * 64 + xx] : 0.f;
            }
        }
        float o00 = 0.f, o01 = 0.f, o10 = 0.f, o11 = 0.f;
#pragma unroll
        for (int kk = 0; kk < 9; kk++) {
            float pv = p[kk / 3][kk % 3];
            o00 += pv * m[0][kk];
            o01 += pv * m[1][kk];
            o10 += pv * m[2][kk];
            o11 += pv * m[3][kk];
        }
        float* ob = out + ((size_t)(b * 256 + c) * 128 + 2 * h) * 128 + 2 * w;
        *(f2*)ob = f2{o00, o01};             // row 2h   (p=0)
        *(f2*)(ob + 128) = f2{o10, o11};     // row 2h+1 (p=1)
    }
}

extern "C" void kernel_launch(void* const* d_in, const int* in_sizes, int n_in,
                              void* d_out, int out_size, void* d_ws, size_t ws_size,
                              hipStream_t stream) {
    const float* x  = (const float*)d_in[0];
    const float* w1 = (const float*)d_in[1];
    const float* b1 = (const float*)d_in[2];
    const float* w2 = (const float*)d_in[3];
    const float* b2 = (const float*)d_in[4];
    float* out = (float*)d_out;
    float* ws  = (float*)d_ws;

    k_init<<<133, 256, 0, stream>>>(w1, w2, ws);
    k_comp<<<512, 128, 0, stream>>>(x, b1, ws);
    k_mask<<<512, 384, 0, stream>>>(b2, ws);
    k_out<<<2048, 256, 0, stream>>>(x, ws, out);
}

// Round 7
// 84.936 us; speedup vs baseline: 1.2368x; 1.2368x over previous
//
#include <hip/hip_runtime.h>

// GGCARAFE: gradient-guided CARAFE upsample, B=8, C=256, H=W=64, K=3, S=2
// R7: revert k_comp to R5 (4-jg, 2048 waves; R6's jsplit=2 gave 1 wave/SIMD).
// Fuse k_mask + k_out: mask lives in LDS, never touches global.
// ws layout (float indices):
//   w1t   [256][64] f32         @ 0        (16384)   w1t[c*64+j] = w1[j][c]
//   mean  [B][H][W] f32         @ 16384    (32768)
//   w2b   [48][576] bf16        @ 49152    (13824 f32-equiv)  w2b[o][s*64+j]
//   comp_p[8][66][66][64] bf16  @ 62976    (1115136 f32-equiv) zero ring
// total 1,178,112 floats = 4.71 MB

#define W1T_OFF   0
#define MEAN_OFF  16384
#define W2B_OFF   49152
#define CPP_OFF   62976

typedef __attribute__((ext_vector_type(8))) short bf8;            // 8 bf16 = 16B
typedef __attribute__((ext_vector_type(8))) unsigned short us8;   // 16B store
typedef __attribute__((ext_vector_type(4))) float f4;
typedef __attribute__((ext_vector_type(2))) float f2;

static __device__ inline unsigned short f2bf(float f) {
    unsigned u = __float_as_uint(f);
    unsigned r = u + 0x7FFFu + ((u >> 16) & 1u);   // RNE
    return (unsigned short)(r >> 16);
}

// k_init: zero comp_p PAD RING only + weight transposes.
__global__ __launch_bounds__(256) void k_init(const float* __restrict__ w1,
                                              const float* __restrict__ w2,
                                              float* __restrict__ ws) {
    int bid = blockIdx.x, t = threadIdx.x;
    if (bid < 65) {
        int id = bid * 256 + t;           // 0..16639
        if (id < 16640) {
            int px = id >> 3, part = id & 7;
            int b = px / 260, r = px % 260;
            int y, xx;
            if (r < 66)       { y = 0;  xx = r; }
            else if (r < 132) { y = 65; xx = r - 66; }
            else              { int s = r - 132; y = (s & 63) + 1; xx = (s >> 6) ? 65 : 0; }
            uint4* p = (uint4*)((unsigned short*)(ws + CPP_OFF)
                                + ((size_t)(b * 66 + y) * 66 + xx) * 64) + part;
            *p = uint4{0, 0, 0, 0};
        }
        return;
    }
    float* w1t = ws + W1T_OFF;
    unsigned short* w2b = (unsigned short*)(ws + W2B_OFF);
    int gid = (bid - 65) * 256 + t;
    int stride = 68 * 256;
    for (int i = gid; i < 64 * 256; i += stride) {       // w1t[c][j] = w1[j][c]
        int c = i >> 6, j = i & 63;
        w1t[i] = w1[j * 256 + c];
    }
    for (int i = gid; i < 48 * 576; i += stride) {       // w2b[o][s*64+j]
        int o = i / 576, k = i % 576;
        int s = k >> 6, j = k & 63;
        w2b[i] = (o < 36) ? f2bf(w2[o * 576 + j * 9 + s]) : (unsigned short)0;
    }
}

// comp_p[b][h+1][w+1][j] bf16; mean fp32. R5-proven structure:
// grid 512 x 256 (2048 waves): jg = blockIdx>>7, pix = (blockIdx&127)*256+tid
__global__ __launch_bounds__(256) void k_comp(const float* __restrict__ x,
                                              const float* __restrict__ b1,
                                              float* __restrict__ ws) {
    const float* w1t = ws + W1T_OFF;
    float* mean = ws + MEAN_OFF;
    unsigned short* cpp = (unsigned short*)(ws + CPP_OFF);
    int jg = blockIdx.x >> 7;                          // uniform
    int pix = ((blockIdx.x & 127) << 8) + threadIdx.x; // 0..32767
    int b = pix >> 12, hw = pix & 4095;
    int h = hw >> 6, wx = hw & 63;
    const float* xp = x + (size_t)b * 256 * 4096 + hw;
    float acc[16];
#pragma unroll
    for (int jj = 0; jj < 16; jj++) acc[jj] = b1[jg * 16 + jj];
    float msum = 0.f;
    for (int c = 0; c < 256; c += 8) {
        float xv[8];
#pragma unroll
        for (int u = 0; u < 8; u++) xv[u] = xp[(size_t)(c + u) * 4096];
#pragma unroll
        for (int u = 0; u < 8; u++) {
            msum += xv[u];
            const float* wp = w1t + (c + u) * 64 + jg * 16;   // uniform -> s_load
#pragma unroll
            for (int jj = 0; jj < 16; jj++) acc[jj] += wp[jj] * xv[u];
        }
    }
    us8 v0, v1;
#pragma unroll
    for (int jj = 0; jj < 8; jj++) { v0[jj] = f2bf(acc[jj]); v1[jj] = f2bf(acc[jj + 8]); }
    unsigned short* dst = cpp + ((size_t)(b * 66 + h + 1) * 66 + (wx + 1)) * 64 + jg * 16;
    *(us8*)dst = v0;
    *(us8*)(dst + 8) = v1;
    if (jg == 0) mean[pix] = msum * (1.f / 256.f);
}

// FUSED mask+out. grid 512 = (b,h) swizzled; block 384 = 6 waves.
// Phase A (R5 k_mask): MFMA kern -> LDS, grad+softmax -> msk LDS.
// Phase B (R6 k_out): reassembly from msk LDS, 4 pq per thread, f2 stores.
__global__ __launch_bounds__(384) void k_fused(const float* __restrict__ x,
                                               const float* __restrict__ b2,
                                               const float* __restrict__ ws,
                                               float* __restrict__ out) {
    const unsigned short* w2b = (const unsigned short*)(ws + W2B_OFF);
    const unsigned short* cpp = (const unsigned short*)(ws + CPP_OFF);
    const float* mean = ws + MEAN_OFF;
    __shared__ float kern[64][49];   // stride 49 (17w%32 coprime): conflict-free
    __shared__ float msk[64][37];    // stride 37 (5w%32 coprime): conflict-free

    int bid = blockIdx.x;
    int swz = (bid & 7) * 64 + (bid >> 3);             // XCD chunking, bijective
    int b = swz >> 6, h = swz & 63;
    int t = threadIdx.x;
    int wid = __builtin_amdgcn_readfirstlane(t >> 6);  // 0..5, wave-uniform
    int l = t & 63;
    int o = wid % 3, ph = wid / 3;
    int lm = l & 15, lk = l >> 4;

    // ---- Phase A: kern GEMM (M=64 px, N=48, K=576) ----
    bf8 bfrag[18];
    const unsigned short* bp = w2b + (size_t)(o * 16 + lm) * 576 + lk * 8;
#pragma unroll
    for (int ks = 0; ks < 18; ks++) bfrag[ks] = *(const bf8*)(bp + ks * 32);

    const unsigned short* abase = cpp + ((size_t)(b * 66 + h) * 66 + lm) * 64 + lk * 8;

#pragma unroll
    for (int hf = 0; hf < 2; hf++) {
        int w0 = (ph * 2 + hf) * 16;
        const unsigned short* ab = abase + w0 * 64;
        f4 acc = {0.f, 0.f, 0.f, 0.f};
#pragma unroll
        for (int ks = 0; ks < 18; ks++) {
            const int s = ks >> 1, jh = ks & 1;
            const int dy = s / 3, dx = s % 3;          // compile-time
            bf8 af = *(const bf8*)(ab + (dy * 66 + dx) * 64 + jh * 32);
            acc = __builtin_amdgcn_mfma_f32_16x16x32_bf16(af, bfrag[ks], acc, 0, 0, 0);
        }
#pragma unroll
        for (int r = 0; r < 4; r++)
            kern[w0 + lk * 4 + r][o * 16 + lm] = acc[r];
    }
    __syncthreads();

    // grad guidance + softmax -> msk LDS; thread (w, pq) for t < 256
    if (t < 256) {
        int w = t & 63, pq = t >> 6;
        float mc = mean[(b * 64 + h) * 64 + w];
        float v[9], mx = -1e30f;
#pragma unroll
        for (int kk = 0; kk < 9; kk++) {
            int y = h + kk / 3 - 1, xw = w + kk % 3 - 1;
            float mv = ((unsigned)y < 64u && (unsigned)xw < 64u)
                           ? mean[(b * 64 + y) * 64 + xw] : 0.f;
            float d = mv - mc;
            float g = 1.f / (d * d + 0.2f);
            v[kk] = g * (kern[w][kk * 4 + pq] + b2[kk * 4 + pq]);
            mx = fmaxf(mx, v[kk]);
        }
        float s = 0.f;
#pragma unroll
        for (int kk = 0; kk < 9; kk++) { v[kk] = __expf(v[kk] - mx); s += v[kk]; }
        float inv = 1.f / s;
#pragma unroll
        for (int kk = 0; kk < 9; kk++) msk[w][pq * 9 + kk] = v[kk] * inv;
    }
    __syncthreads();

    // ---- Phase B: reassembly. thread (w = t&63, cs = t>>6 in 0..5) ----
    int w = t & 63, cs = t >> 6;
    float m[4][9];
#pragma unroll
    for (int pq = 0; pq < 4; pq++)
#pragma unroll
        for (int kk = 0; kk < 9; kk++) m[pq][kk] = msk[w][pq * 9 + kk];

    for (int c = cs; c < 256; c += 6) {
        const float* xb = x + (size_t)(b * 256 + c) * 4096;
        float p[3][3];
#pragma unroll
        for (int dy = 0; dy < 3; dy++) {
            int y = h + dy - 1;
            bool yok = (unsigned)y < 64u;
#pragma unroll
            for (int dx = 0; dx < 3; dx++) {
                int xx = w + dx - 1;
                p[dy][dx] = (yok && (unsigned)xx < 64u) ? xb[y * 64 + xx] : 0.f;
            }
        }
        float o00 = 0.f, o01 = 0.f, o10 = 0.f, o11 = 0.f;
#pragma unroll
        for (int kk = 0; kk < 9; kk++) {
            float pv = p[kk / 3][kk % 3];
            o00 += pv * m[0][kk];
            o01 += pv * m[1][kk];
            o10 += pv * m[2][kk];
            o11 += pv * m[3][kk];
        }
        float* ob = out + ((size_t)(b * 256 + c) * 128 + 2 * h) * 128 + 2 * w;
        *(f2*)ob = f2{o00, o01};             // row 2h   (p=0)
        *(f2*)(ob + 128) = f2{o10, o11};     // row 2h+1 (p=1)
    }
}

extern "C" void kernel_launch(void* const* d_in, const int* in_sizes, int n_in,
                              void* d_out, int out_size, void* d_ws, size_t ws_size,
                              hipStream_t stream) {
    const float* x  = (const float*)d_in[0];
    const float* w1 = (const float*)d_in[1];
    const float* b1 = (const float*)d_in[2];
    const float* w2 = (const float*)d_in[3];
    const float* b2 = (const float*)d_in[4];
    float* out = (float*)d_out;
    float* ws  = (float*)d_ws;

    k_init<<<133, 256, 0, stream>>>(w1, w2, ws);
    k_comp<<<512, 256, 0, stream>>>(x, b1, ws);
    k_fused<<<512, 384, 0, stream>>>(x, b2, ws, out);
}